// Round 7
// baseline (269.463 us; speedup 1.0000x reference)
//
#include <hip/hip_runtime.h>
#include <cstdint>

// ---------------------------------------------------------------------------
// AriaTextMoELayer R7: transpose pass rebuilt for memory-level parallelism:
// fp32 tile staged to LDS via global_load_lds (DMA, 8 outstanding 1KB ops per
// wave, XOR-preswizzled source), conflict-free ds_read_b128 column gather,
// bf16 pack, swizzled LDS restage, contiguous 16KB global write-out.
// GEMMs identical to R6 (tile-contiguous B, dbuf, gl16, atomicAdd epilogue).
// ---------------------------------------------------------------------------

#define E_ 8
#define H_ 1024
#define I_ 1024
#define ISH_ 2048
#define NTOK 2048

typedef unsigned short u16;
using bf16x8 = __attribute__((ext_vector_type(8))) __bf16;
using f32x4  = __attribute__((ext_vector_type(4))) float;

__device__ __forceinline__ u16 f2bf(float f) {
  union { float f; unsigned u; } v; v.f = f;
  unsigned r = v.u + 0x7fffu + ((v.u >> 16) & 1u);  // RNE
  return (u16)(r >> 16);
}
__device__ __forceinline__ unsigned pk2(float lo, float hi) {
  return ((unsigned)f2bf(hi) << 16) | (unsigned)f2bf(lo);
}

typedef __attribute__((address_space(1))) const void glb_v;
typedef __attribute__((address_space(3))) void lds_v;
__device__ __forceinline__ void gl16(const void* g, void* l) {
  __builtin_amdgcn_global_load_lds((glb_v*)g, (lds_v*)l, 16, 0, 0);
}
__device__ __forceinline__ f32x4 mfma16(bf16x8 a, bf16x8 b, f32x4 c) {
  return __builtin_amdgcn_mfma_f32_16x16x32_bf16(a, b, c, 0, 0, 0);
}

// ---------------- router core ----------------
__device__ __forceinline__ void router_body(const float* __restrict__ x,
                                            const float* __restrict__ wr,
                                            float* __restrict__ scores,
                                            int* __restrict__ cnt,
                                            int* __restrict__ list, int tk) {
  int lane = threadIdx.x & 63;
  const float* xr = x + (size_t)tk * H_;
  float acc[E_];
#pragma unroll
  for (int e = 0; e < E_; ++e) acc[e] = 0.f;
  int h0 = lane * 16;
#pragma unroll 4
  for (int i = 0; i < 16; ++i) {
    float xv = xr[h0 + i];
    const float* w = wr + (size_t)(h0 + i) * E_;
#pragma unroll
    for (int e = 0; e < E_; ++e) acc[e] = fmaf(xv, w[e], acc[e]);
  }
#pragma unroll
  for (int off = 32; off > 0; off >>= 1) {
#pragma unroll
    for (int e = 0; e < E_; ++e) acc[e] += __shfl_xor(acc[e], off, 64);
  }
  if (lane == 0) {
    int e0 = 0; float m0 = acc[0];
#pragma unroll
    for (int e = 1; e < E_; ++e) if (acc[e] > m0) { m0 = acc[e]; e0 = e; }
    int e1 = -1; float m1 = -1e30f;
#pragma unroll
    for (int e = 0; e < E_; ++e) if (e != e0 && acc[e] > m1) { m1 = acc[e]; e1 = e; }
    float s0 = 1.f / (1.f + __expf(m1 - m0));
    scores[tk * 2 + 0] = s0;
    scores[tk * 2 + 1] = 1.f - s0;
    int p0 = atomicAdd(&cnt[e0], 1); list[e0 * NTOK + p0] = tk * 2;
    int p1 = atomicAdd(&cnt[e1], 1); list[e1 * NTOK + p1] = tk * 2 + 1;
  }
}

// ---------------- transpose-convert, MLP-optimized ---------------------------
// src fp32 [K][N] -> dst bf16 tiles [nt][kt][128n][32k] (8KB contiguous).
// Block: k-span kb*64..+63, n-span nb*128..+127.
// Stage1: gl16 DMA src->bufA (fp32 [64][128], source chunk-XOR so stage2 is
// conflict-free). Stage2: ds_read_b128 column gather + bf16 pack. Stage3:
// swizzled ds_write_b128 -> bufB (2 tiles). Stage4: linear 16KB write-out.
__device__ __forceinline__ void wtrans3(const float* __restrict__ src,
                                        u16* __restrict__ dst, int K, int N,
                                        int kb, int nb, void* smem) {
  float* bufA = (float*)smem;                         // 32 KB
  u16*   bufB = (u16*)((char*)smem + 32768);          // 16 KB
  int t = threadIdx.x, lane = t & 63, w = t >> 6;

  // stage 1: 8 outstanding gl16 per wave; lane source pre-swizzled
  const float* sbase = src + (size_t)(kb * 64) * N + nb * 128;
#pragma unroll
  for (int i = 0; i < 8; ++i) {
    int g = w * 8 + i;                    // 1 KB op -> rows 2g, 2g+1
    int k = 2 * g + (lane >> 5);
    int sc = (lane & 31) ^ (k & 31);      // source 16B chunk (XOR preswizzle)
    gl16(sbase + (size_t)k * N + sc * 4, (char*)bufA + g * 1024);
  }
  __syncthreads();

  // stage 2: thread (n4 = t&31, kg = t>>5) gathers 8 k-rows of its 16B n-chunk
  int n4 = t & 31, kg = t >> 5;
  float4 v[8];
#pragma unroll
  for (int j = 0; j < 8; ++j) {
    int k = kg * 8 + j;
    v[j] = *(const float4*)((const char*)bufA + k * 512 + ((n4 ^ (k & 31)) << 4));
  }
  // stage 3: pack 8k x 4n -> four 16B units into bufB (chunk-XOR swizzled)
  int s = kg >> 2, c = kg & 3;
#pragma unroll
  for (int i = 0; i < 4; ++i) {
    int n = n4 * 4 + i;
    const float* f0 = (const float*)&v[0];
    uint4 o;
    o.x = pk2(((const float*)&v[0])[i], ((const float*)&v[1])[i]);
    o.y = pk2(((const float*)&v[2])[i], ((const float*)&v[3])[i]);
    o.z = pk2(((const float*)&v[4])[i], ((const float*)&v[5])[i]);
    o.w = pk2(((const float*)&v[6])[i], ((const float*)&v[7])[i]);
    int cs = c ^ ((n >> 3) & 3);
    *(uint4*)((char*)bufB + s * 8192 + n * 64 + cs * 16) = o;
    (void)f0;
  }
  __syncthreads();

  // stage 4: contiguous 16 KB write-out (un-swizzle on LDS read)
  int ktiles = K >> 5;
  u16* tb = dst + (size_t)(nb * ktiles + kb * 2) * 4096;
#pragma unroll
  for (int r = 0; r < 4; ++r) {
    int u = r * 256 + t;                 // 16B unit index, ordered (s, n, q)
    int s2 = u >> 9, rem = u & 511, n = rem >> 2, q = rem & 3;
    uint4 o = *(const uint4*)((const char*)bufB + s2 * 8192 + n * 64 +
                              ((q ^ ((n >> 3) & 3)) << 4));
    *(uint4*)(tb + (size_t)s2 * 4096 + n * 32 + q * 8) = o;
  }
}

// ================= FAST PATH =================

// prep3: [0,512) router | [512,1024) x->bf16 | [1024,3072) fc1 |
// [3072,3328) gw | [3328,3584) uw | [3584,4608) fc2 | [4608,4864) dw
__global__ __launch_bounds__(256) void prep3_k(
    const float* __restrict__ x, const float* __restrict__ wr,
    float* __restrict__ scores, int* __restrict__ cnt, int* __restrict__ list,
    u16* __restrict__ xb,
    const float* __restrict__ fc1, const float* __restrict__ fc2,
    const float* __restrict__ gw, const float* __restrict__ uw,
    const float* __restrict__ dw,
    u16* __restrict__ fc1T, u16* __restrict__ fc2T, u16* __restrict__ gwT,
    u16* __restrict__ uwT, u16* __restrict__ dwT) {
  __shared__ __align__(16) char psm[49152];
  int bid = blockIdx.x, t = threadIdx.x;
  if (bid < 512) {
    router_body(x, wr, scores, cnt, list, bid * 4 + (t >> 6));
    return;
  }
  if (bid < 1024) {
    const float4* srcx = (const float4*)x;
    ushort4* dstx = (ushort4*)xb;
    int base = (bid - 512) * 1024 + t;
#pragma unroll
    for (int it = 0; it < 4; ++it) {
      float4 v = srcx[base + it * 256];
      ushort4 o;
      o.x = f2bf(v.x); o.y = f2bf(v.y); o.z = f2bf(v.z); o.w = f2bf(v.w);
      dstx[base + it * 256] = o;
    }
    return;
  }
  if (bid < 3072) {        // fc1: 8 x [1024][2048]: kb 0..15, nb 0..15
    int b = bid - 1024;
    int e = b >> 8, q = b & 255;
    wtrans3(fc1 + ((size_t)e << 21), fc1T + ((size_t)e << 21), 1024, 2048,
            q & 15, q >> 4, psm);
  } else if (bid < 3328) { // gw [1024][2048]
    int q = bid - 3072;
    wtrans3(gw, gwT, 1024, 2048, q & 15, q >> 4, psm);
  } else if (bid < 3584) { // uw [1024][2048]
    int q = bid - 3328;
    wtrans3(uw, uwT, 1024, 2048, q & 15, q >> 4, psm);
  } else if (bid < 4608) { // fc2: 8 x [1024][1024]: kb 0..15, nb 0..7
    int b = bid - 3584;
    int e = b >> 7, q = b & 127;
    wtrans3(fc2 + ((size_t)e << 20), fc2T + ((size_t)e << 20), 1024, 1024,
            q & 15, q >> 4, psm);
  } else {                 // dw [2048][1024]: kb 0..31, nb 0..7
    int q = bid - 4608;
    wtrans3(dw, dwT, 2048, 1024, q & 31, q >> 5, psm);
  }
}

// L1: fused SwiGLU GEMMs, dbuf, tiled-B linear staging.
// bid<256: G3 dense (gwT/uwT); else G1 expert (fc1T). 128x128, BK=32.
__global__ __launch_bounds__(256, 2) void swiglu3_k(
    const u16* __restrict__ xb, const int* __restrict__ cnt,
    const int* __restrict__ list, const u16* __restrict__ fc1T,
    const u16* __restrict__ gwT, const u16* __restrict__ uwT,
    u16* __restrict__ act, u16* __restrict__ tmp) {
  __shared__ __align__(16) u16 As[2][4096];
  __shared__ __align__(16) u16 B1s[2][4096];
  __shared__ __align__(16) u16 B2s[2][4096];

  int bid = blockIdx.x;
  int m0, n0, Me, obase = 0, ldo;
  const u16 *B1, *B2;  // tile-sequence base; k-tile kt at +kt*4096
  const int* rowmap = nullptr;
  u16* Out;
  if (bid < 256) {  // G3 shared experts: gw/uw [1024][2048] -> nt=nb, 32 kt
    int mb = bid >> 4, nb = bid & 15;
    m0 = mb * 128; n0 = nb * 128; Me = NTOK;
    B1 = gwT + (size_t)(nb * 32) * 4096;
    B2 = uwT + (size_t)(nb * 32) * 4096;
    Out = tmp; ldo = ISH_;
  } else {  // G1 expert fc1: proj nt=nb, gate nt=8+nb
    int b2 = bid - 256; int e = b2 >> 7, r = b2 & 127, mb = r >> 3, nb = r & 7;
    Me = cnt[e]; m0 = mb * 128;
    if (m0 >= Me) return;
    n0 = nb * 128;
    rowmap = list + e * NTOK;
    const u16* fe = fc1T + ((size_t)e << 21);
    B1 = fe + (size_t)(nb * 32) * 4096;
    B2 = fe + (size_t)((8 + nb) * 32) * 4096;
    int off = 0;
    for (int q = 0; q < e; ++q) off += cnt[q];
    obase = off; Out = act; ldo = I_;
  }
  int t = threadIdx.x, wid = t >> 6, lane = t & 63;
  int wm = wid & 1, wn = wid >> 1, lr = lane & 15, lkg = lane >> 4;
  int cq = lane & 3, crw = lane >> 2;

  const u16* arow[2];
#pragma unroll
  for (int i = 0; i < 2; ++i) {
    int c = wid * 2 + i;
    int rl = m0 + c * 16 + crw;
    int rc = rl < Me ? rl : (Me - 1);
    int tok = rowmap ? (rowmap[rc] >> 1) : rc;
    arow[i] = xb + (size_t)tok * 1024 + cq * 8;
  }

  auto stage = [&](int cb, int kt) {
#pragma unroll
    for (int i = 0; i < 2; ++i) {
      int c = wid * 2 + i;
      int bo = wid * 1024 + i * 512;
      gl16(arow[i] + kt * 32, As[cb] + c * 512);
      gl16(B1 + kt * 4096 + bo + lane * 8, B1s[cb] + bo);
      gl16(B2 + kt * 4096 + bo + lane * 8, B2s[cb] + bo);
    }
  };

  f32x4 aP[4][4] = {}, aG[4][4] = {};
  auto compute = [&](int cb) {
    bf16x8 af[4];
#pragma unroll
    for (int f = 0; f < 4; ++f)
      af[f] = *(const bf16x8*)(As[cb] + (wm * 64 + f * 16 + lr) * 32 + lkg * 8);
#pragma unroll
    for (int fn = 0; fn < 4; ++fn) {
      bf16x8 b1 = *(const bf16x8*)(B1s[cb] + (wn * 64 + fn * 16 + lr) * 32 + lkg * 8);
      bf16x8 b2 = *(const bf16x8*)(B2s[cb] + (wn * 64 + fn * 16 + lr) * 32 + lkg * 8);
#pragma unroll
      for (int fm = 0; fm < 4; ++fm) {
        aP[fm][fn] = mfma16(af[fm], b1, aP[fm][fn]);
        aG[fm][fn] = mfma16(af[fm], b2, aG[fm][fn]);
      }
    }
  };

  stage(0, 0);
  __syncthreads();
  int cur = 0;
  for (int kt = 1; kt < 32; ++kt) {
    stage(cur ^ 1, kt);
    compute(cur);
    __syncthreads();
    cur ^= 1;
  }
  compute(cur);

#pragma unroll
  for (int fm = 0; fm < 4; ++fm)
#pragma unroll
    for (int fn = 0; fn < 4; ++fn)
#pragma unroll
      for (int j = 0; j < 4; ++j) {
        int row = m0 + wm * 64 + fm * 16 + lkg * 4 + j;
        if (row < Me) {
          float p = aP[fm][fn][j], g = aG[fm][fn][j];
          float s = p / (1.f + __expf(-p)) * g;
          Out[(size_t)(obase + row) * ldo + n0 + wn * 64 + fn * 16 + lr] = f2bf(s);
        }
      }
}

// L2: fused fc2 + down GEMMs (both BN=128), dbuf, atomicAdd fp32 epilogue.
// bid<1024: fc2 expert e -> out[token] += v*score. else: down split-K2.
__global__ __launch_bounds__(256, 2) void out3_k(
    const u16* __restrict__ act, const u16* __restrict__ fc2T,
    const u16* __restrict__ tmp, const u16* __restrict__ dwT,
    const int* __restrict__ cnt, const int* __restrict__ list,
    const float* __restrict__ scores, float* __restrict__ out) {
  __shared__ __align__(16) u16 As[2][4096];
  __shared__ __align__(16) u16 Bs[2][4096];

  int bid = blockIdx.x;
  int Me, m0, n0, lda, akoff = 0, mode, e = 0;
  const u16 *Ab, *Bt;
  const int* listE = nullptr;
  if (bid < 1024) {  // fc2: [1024][1024] tiled: nt=nb(8), 32 kt
    e = bid >> 7; int r = bid & 127, mb = r >> 3, nb = r & 7;
    Me = cnt[e]; m0 = mb * 128;
    if (m0 >= Me) return;
    n0 = nb * 128;
    int off = 0;
    for (int q = 0; q < e; ++q) off += cnt[q];
    Ab = act + (size_t)off * 1024; lda = 1024;
    Bt = fc2T + ((size_t)e << 20) + (size_t)(nb * 32) * 4096;
    listE = list + e * NTOK; mode = 0;
  } else {  // down: dw [2048][1024] tiled: nt=nb(8), 64 kt; ks picks 32
    int r = bid - 1024, ks = r >> 7, rr = r & 127, mb = rr >> 3, nb = rr & 7;
    Me = NTOK; m0 = mb * 128; n0 = nb * 128;
    Ab = tmp; lda = 2048; akoff = ks * 1024;
    Bt = dwT + (size_t)(nb * 64 + ks * 32) * 4096;
    mode = 1;
  }
  int t = threadIdx.x, wid = t >> 6, lane = t & 63;
  int wm = wid & 1, wn = wid >> 1, lr = lane & 15, lkg = lane >> 4;
  int cq = lane & 3, crw = lane >> 2;

  const u16* arow[2];
#pragma unroll
  for (int i = 0; i < 2; ++i) {
    int c = wid * 2 + i;
    int rl = m0 + c * 16 + crw;
    int rc = rl < Me ? rl : (Me - 1);
    arow[i] = Ab + (size_t)rc * lda + akoff + cq * 8;
  }

  auto stage = [&](int cb, int kt) {
#pragma unroll
    for (int i = 0; i < 2; ++i) {
      int c = wid * 2 + i;
      int bo = wid * 1024 + i * 512;
      gl16(arow[i] + kt * 32, As[cb] + c * 512);
      gl16(Bt + kt * 4096 + bo + lane * 8, Bs[cb] + bo);
    }
  };

  f32x4 acc[4][4] = {};
  auto compute = [&](int cb) {
    bf16x8 af[4];
#pragma unroll
    for (int f = 0; f < 4; ++f)
      af[f] = *(const bf16x8*)(As[cb] + (wm * 64 + f * 16 + lr) * 32 + lkg * 8);
#pragma unroll
    for (int fn = 0; fn < 4; ++fn) {
      bf16x8 bb = *(const bf16x8*)(Bs[cb] + (wn * 64 + fn * 16 + lr) * 32 + lkg * 8);
#pragma unroll
      for (int fm = 0; fm < 4; ++fm)
        acc[fm][fn] = mfma16(af[fm], bb, acc[fm][fn]);
    }
  };

  stage(0, 0);
  __syncthreads();
  int cur = 0;
  for (int kt = 1; kt < 32; ++kt) {
    stage(cur ^ 1, kt);
    compute(cur);
    __syncthreads();
    cur ^= 1;
  }
  compute(cur);

#pragma unroll
  for (int fm = 0; fm < 4; ++fm)
#pragma unroll
    for (int fn = 0; fn < 4; ++fn)
#pragma unroll
      for (int j = 0; j < 4; ++j) {
        int row = m0 + wm * 64 + fm * 16 + lkg * 4 + j;
        if (row < Me) {
          float v = acc[fm][fn][j];
          int c = n0 + wn * 64 + fn * 16 + lr;
          if (mode == 0) {
            int slot = listE[row];
            atomicAdd(&out[(size_t)(slot >> 1) * H_ + c], v * scores[slot]);
          } else {
            atomicAdd(&out[(size_t)row * H_ + c], v);
          }
        }
      }
}

// ================= FALLBACK PATH (R1, proven) =================
#define BM 128
#define BN 64
#define BK 32
#define PK (BK + 8)

__global__ void router_k(const float* __restrict__ x, const float* __restrict__ wr,
                         float* __restrict__ scores, int* __restrict__ cnt,
                         int* __restrict__ list) {
  int wid = threadIdx.x >> 6;
  int tk = blockIdx.x * 4 + wid;
  if (tk >= NTOK) return;
  router_body(x, wr, scores, cnt, list, tk);
}

__global__ void offs_k(const int* __restrict__ cnt, int* __restrict__ offs) {
  if (threadIdx.x == 0 && blockIdx.x == 0) {
    int s = 0;
    for (int e = 0; e < E_; ++e) { offs[e] = s; s += cnt[e]; }
  }
}

__global__ void cvt_k(const float* __restrict__ x, u16* __restrict__ xb, int n4) {
  int i = blockIdx.x * blockDim.x + threadIdx.x;
  if (i >= n4) return;
  float4 v = reinterpret_cast<const float4*>(x)[i];
  ushort4 o;
  o.x = f2bf(v.x); o.y = f2bf(v.y); o.z = f2bf(v.z); o.w = f2bf(v.w);
  reinterpret_cast<ushort4*>(xb)[i] = o;
}

template <int EXPERT>
__global__ __launch_bounds__(256) void swiglu_gemm_k(
    const u16* __restrict__ A, int lda,
    const int* __restrict__ list, const int* __restrict__ cnt, const int* __restrict__ offs,
    const float* __restrict__ B1g, const float* __restrict__ B2g, int ldb, long long bstride,
    u16* __restrict__ Out, int ldo, int K) {
  __shared__ u16 As[BM][PK];
  __shared__ u16 Bs[2][BN][PK];
  int e = EXPERT ? blockIdx.z : 0;
  int Me = EXPERT ? cnt[e] : NTOK;
  int m0 = blockIdx.y * BM;
  if (m0 >= Me) return;
  int n0 = blockIdx.x * BN;
  const int* rowmap = EXPERT ? (list + e * NTOK) : nullptr;
  const float* B1 = B1g + (EXPERT ? (long long)e * bstride : 0);
  const float* B2 = B2g + (EXPERT ? (long long)e * bstride : 0);
  int t = threadIdx.x, wid = t >> 6, lane = t & 63;
  int wm = wid & 1, wn = wid >> 1, lr = lane & 15, lkg = lane >> 4;
  f32x4 accP[4][2] = {}, accG[4][2] = {};
  for (int k0 = 0; k0 < K; k0 += BK) {
#pragma unroll
    for (int it = 0; it < 2; ++it) {
      int idx = it * 256 + t, r = idx >> 2, q = idx & 3, row = m0 + r;
      uint4 v = make_uint4(0u, 0u, 0u, 0u);
      if (row < Me) {
        int rg = EXPERT ? (rowmap[row] >> 1) : row;
        v = *reinterpret_cast<const uint4*>(A + (size_t)rg * lda + k0 + q * 8);
      }
      *reinterpret_cast<uint4*>(&As[r][q * 8]) = v;
    }
#pragma unroll
    for (int b = 0; b < 2; ++b) {
      const float* Bp = b ? B2 : B1;
#pragma unroll
      for (int it = 0; it < 2; ++it) {
        int idx = (it * 256 + t) * 4, kr = idx >> 6, c = idx & 63;
        float4 f = *reinterpret_cast<const float4*>(Bp + (size_t)(k0 + kr) * ldb + n0 + c);
        Bs[b][c + 0][kr] = f2bf(f.x); Bs[b][c + 1][kr] = f2bf(f.y);
        Bs[b][c + 2][kr] = f2bf(f.z); Bs[b][c + 3][kr] = f2bf(f.w);
      }
    }
    __syncthreads();
    bf16x8 af[4];
#pragma unroll
    for (int fm = 0; fm < 4; ++fm)
      af[fm] = *reinterpret_cast<const bf16x8*>(&As[wm * 64 + fm * 16 + lr][lkg * 8]);
#pragma unroll
    for (int fn = 0; fn < 2; ++fn) {
      bf16x8 bp = *reinterpret_cast<const bf16x8*>(&Bs[0][wn * 32 + fn * 16 + lr][lkg * 8]);
      bf16x8 bg = *reinterpret_cast<const bf16x8*>(&Bs[1][wn * 32 + fn * 16 + lr][lkg * 8]);
#pragma unroll
      for (int fm = 0; fm < 4; ++fm) {
        accP[fm][fn] = __builtin_amdgcn_mfma_f32_16x16x32_bf16(af[fm], bp, accP[fm][fn], 0, 0, 0);
        accG[fm][fn] = __builtin_amdgcn_mfma_f32_16x16x32_bf16(af[fm], bg, accG[fm][fn], 0, 0, 0);
      }
    }
    __syncthreads();
  }
#pragma unroll
  for (int fm = 0; fm < 4; ++fm)
#pragma unroll
    for (int fn = 0; fn < 2; ++fn)
#pragma unroll
      for (int j = 0; j < 4; ++j) {
        int grow = wm * 64 + fm * 16 + lkg * 4 + j, gcol = wn * 32 + fn * 16 + lr;
        int row = m0 + grow;
        if (row < Me) {
          float p = accP[fm][fn][j], g = accG[fm][fn][j];
          float s = p / (1.f + __expf(-p)) * g;
          int orow = EXPERT ? (offs[e] + row) : row;
          Out[(size_t)orow * ldo + n0 + gcol] = f2bf(s);
        }
      }
}

template <int EXPERT>
__global__ __launch_bounds__(256) void out_gemm_k(
    const u16* __restrict__ A, int lda,
    const int* __restrict__ cnt, const int* __restrict__ offs,
    const int* __restrict__ list, const float* __restrict__ scores,
    const float* __restrict__ Bg, int ldb, long long bstride,
    float* __restrict__ Out, const float* __restrict__ outbuf, int K) {
  __shared__ u16 As[BM][PK];
  __shared__ u16 Bs[BN][PK];
  int e = EXPERT ? blockIdx.z : 0;
  int Me = EXPERT ? cnt[e] : NTOK;
  int m0 = blockIdx.y * BM;
  if (m0 >= Me) return;
  int n0 = blockIdx.x * BN;
  const float* B = Bg + (EXPERT ? (long long)e * bstride : 0);
  int aoff = EXPERT ? offs[e] : 0;
  int t = threadIdx.x, wid = t >> 6, lane = t & 63;
  int wm = wid & 1, wn = wid >> 1, lr = lane & 15, lkg = lane >> 4;
  f32x4 acc[4][2] = {};
  for (int k0 = 0; k0 < K; k0 += BK) {
#pragma unroll
    for (int it = 0; it < 2; ++it) {
      int idx = it * 256 + t, r = idx >> 2, q = idx & 3, row = m0 + r;
      uint4 v = make_uint4(0u, 0u, 0u, 0u);
      if (row < Me)
        v = *reinterpret_cast<const uint4*>(A + (size_t)(aoff + row) * lda + k0 + q * 8);
      *reinterpret_cast<uint4*>(&As[r][q * 8]) = v;
    }
#pragma unroll
    for (int it = 0; it < 2; ++it) {
      int idx = (it * 256 + t) * 4, kr = idx >> 6, c = idx & 63;
      float4 f = *reinterpret_cast<const float4*>(B + (size_t)(k0 + kr) * ldb + n0 + c);
      Bs[c + 0][kr] = f2bf(f.x); Bs[c + 1][kr] = f2bf(f.y);
      Bs[c + 2][kr] = f2bf(f.z); Bs[c + 3][kr] = f2bf(f.w);
    }
    __syncthreads();
    bf16x8 af[4];
#pragma unroll
    for (int fm = 0; fm < 4; ++fm)
      af[fm] = *reinterpret_cast<const bf16x8*>(&As[wm * 64 + fm * 16 + lr][lkg * 8]);
#pragma unroll
    for (int fn = 0; fn < 2; ++fn) {
      bf16x8 bb = *reinterpret_cast<const bf16x8*>(&Bs[wn * 32 + fn * 16 + lr][lkg * 8]);
#pragma unroll
      for (int fm = 0; fm < 4; ++fm)
        acc[fm][fn] = __builtin_amdgcn_mfma_f32_16x16x32_bf16(af[fm], bb, acc[fm][fn], 0, 0, 0);
    }
    __syncthreads();
  }
#pragma unroll
  for (int fm = 0; fm < 4; ++fm)
#pragma unroll
    for (int fn = 0; fn < 2; ++fn)
#pragma unroll
      for (int j = 0; j < 4; ++j) {
        int grow = wm * 64 + fm * 16 + lkg * 4 + j, gcol = wn * 32 + fn * 16 + lr;
        int row = m0 + grow;
        if (row < Me) {
          float v = acc[fm][fn][j];
          int c = n0 + gcol;
          if (EXPERT) {
            int slot = list[e * NTOK + row];
            Out[(size_t)slot * H_ + c] = v * scores[slot];
          } else {
            Out[(size_t)row * H_ + c] =
                v + outbuf[(size_t)(2 * row) * H_ + c] + outbuf[(size_t)(2 * row + 1) * H_ + c];
          }
        }
      }
}

// ---------------------------------------------------------------------------
extern "C" void kernel_launch(void* const* d_in, const int* in_sizes, int n_in,
                              void* d_out, int out_size, void* d_ws, size_t ws_size,
                              hipStream_t stream) {
  const float* x   = (const float*)d_in[0];
  const float* wr  = (const float*)d_in[1];
  const float* fc1 = (const float*)d_in[2];
  const float* fc2 = (const float*)d_in[3];
  const float* gw  = (const float*)d_in[4];
  const float* uw  = (const float*)d_in[5];
  const float* dw  = (const float*)d_in[6];
  float* out = (float*)d_out;
  char* ws = (char*)d_ws;

  const size_t NEED_FAST = 131072ull + (88ull << 20);
  if (ws_size >= NEED_FAST) {
    float* scores = (float*)ws;
    int* cnt  = (int*)(ws + 16384);
    int* list = (int*)(ws + 16512);
    u16* xb   = (u16*)(ws + 131072);
    u16* act  = (u16*)(ws + 131072 + (4ll << 20));
    u16* tmp  = (u16*)(ws + 131072 + (12ll << 20));
    u16* fc1T = (u16*)(ws + 131072 + (28ll << 20));
    u16* fc2T = (u16*)(ws + 131072 + (60ll << 20));
    u16* gwT  = (u16*)(ws + 131072 + (76ll << 20));
    u16* uwT  = (u16*)(ws + 131072 + (80ll << 20));
    u16* dwT  = (u16*)(ws + 131072 + (84ll << 20));

    hipMemsetAsync(cnt, 0, 128, stream);
    hipMemsetAsync(out, 0, (size_t)NTOK * H_ * sizeof(float), stream);
    prep3_k<<<4864, 256, 0, stream>>>(x, wr, scores, cnt, list, xb,
                                      fc1, fc2, gw, uw, dw,
                                      fc1T, fc2T, gwT, uwT, dwT);
    swiglu3_k<<<1280, 256, 0, stream>>>(xb, cnt, list, fc1T, gwT, uwT, act, tmp);
    out3_k<<<1280, 256, 0, stream>>>(act, fc2T, tmp, dwT, cnt, list, scores, out);
  } else {
    float* scores = (float*)(ws);
    int*   cnt    = (int*)(ws + (16 << 10));
    int*   offs   = (int*)(ws + (16 << 10) + 128);
    int*   list   = (int*)(ws + (16 << 10) + 256);
    u16*   xb     = (u16*)(ws + (96 << 10));
    u16*   act    = (u16*)(ws + (96 << 10) + (4ll << 20));
    u16*   tmp    = (u16*)(ws + (96 << 10) + (12ll << 20));
    float* outbuf = (float*)(ws + (96 << 10) + (20ll << 20));

    hipMemsetAsync(cnt, 0, E_ * sizeof(int), stream);
    router_k<<<NTOK / 4, 256, 0, stream>>>(x, wr, scores, cnt, list);
    offs_k<<<1, 64, 0, stream>>>(cnt, offs);
    cvt_k<<<(NTOK * H_ / 4 + 255) / 256, 256, 0, stream>>>(x, xb, NTOK * H_ / 4);
    swiglu_gemm_k<1><<<dim3(I_ / BN, NTOK / BM, E_), 256, 0, stream>>>(
        xb, H_, list, cnt, offs, fc1, fc1 + I_, 2 * I_, (long long)H_ * 2 * I_, act, I_, H_);
    out_gemm_k<1><<<dim3(H_ / BN, NTOK / BM, E_), 256, 0, stream>>>(
        act, I_, cnt, offs, list, scores, fc2, H_, (long long)I_ * H_, outbuf, nullptr, I_);
    swiglu_gemm_k<0><<<dim3(ISH_ / BN, NTOK / BM, 1), 256, 0, stream>>>(
        xb, H_, nullptr, nullptr, nullptr, gw, uw, ISH_, 0, tmp, ISH_, H_);
    out_gemm_k<0><<<dim3(H_ / BN, NTOK / BM, 1), 256, 0, stream>>>(
        tmp, ISH_, nullptr, nullptr, nullptr, nullptr, dw, H_, 0, out, outbuf, ISH_);
  }
  (void)in_sizes; (void)n_in; (void)out_size;
}

// Round 10
// 259.358 us; speedup vs baseline: 1.0390x; 1.0390x over previous
//
#include <hip/hip_runtime.h>
#include <cstdint>

// ---------------------------------------------------------------------------
// AriaTextMoELayer R10: k8-blocked weight layout W8[kb][N][8k] (bf16).
// prep: pure-streaming convert (linear reads of 8 full rows, linear writes of
// [n][8k] units) - no strided global access anywhere. GEMMs stage B slabs
// with linear gl16 and read fragments with plain ds_read_b128 (lane's 16B =
// its MFMA B-operand k-octet). A-path/dbuf/epilogues = R6-proven. Fixed the
// R8/R9 OOB: xb convert uses 256 blocks (2M floats), not 512.
// ---------------------------------------------------------------------------

#define E_ 8
#define H_ 1024
#define I_ 1024
#define ISH_ 2048
#define NTOK 2048

typedef unsigned short u16;
using bf16x8 = __attribute__((ext_vector_type(8))) __bf16;
using f32x4  = __attribute__((ext_vector_type(4))) float;

__device__ __forceinline__ u16 f2bf(float f) {
  union { float f; unsigned u; } v; v.f = f;
  unsigned r = v.u + 0x7fffu + ((v.u >> 16) & 1u);  // RNE
  return (u16)(r >> 16);
}

typedef __attribute__((address_space(1))) const void glb_v;
typedef __attribute__((address_space(3))) void lds_v;
__device__ __forceinline__ void gl16(const void* g, void* l) {
  __builtin_amdgcn_global_load_lds((glb_v*)g, (lds_v*)l, 16, 0, 0);
}
__device__ __forceinline__ f32x4 mfma16(bf16x8 a, bf16x8 b, f32x4 c) {
  return __builtin_amdgcn_mfma_f32_16x16x32_bf16(a, b, c, 0, 0, 0);
}

// ---------------- router core ----------------
__device__ __forceinline__ void router_body(const float* __restrict__ x,
                                            const float* __restrict__ wr,
                                            float* __restrict__ scores,
                                            int* __restrict__ cnt,
                                            int* __restrict__ list, int tk) {
  int lane = threadIdx.x & 63;
  const float* xr = x + (size_t)tk * H_;
  float acc[E_];
#pragma unroll
  for (int e = 0; e < E_; ++e) acc[e] = 0.f;
  int h0 = lane * 16;
#pragma unroll 4
  for (int i = 0; i < 16; ++i) {
    float xv = xr[h0 + i];
    const float* w = wr + (size_t)(h0 + i) * E_;
#pragma unroll
    for (int e = 0; e < E_; ++e) acc[e] = fmaf(xv, w[e], acc[e]);
  }
#pragma unroll
  for (int off = 32; off > 0; off >>= 1) {
#pragma unroll
    for (int e = 0; e < E_; ++e) acc[e] += __shfl_xor(acc[e], off, 64);
  }
  if (lane == 0) {
    int e0 = 0; float m0 = acc[0];
#pragma unroll
    for (int e = 1; e < E_; ++e) if (acc[e] > m0) { m0 = acc[e]; e0 = e; }
    int e1 = -1; float m1 = -1e30f;
#pragma unroll
    for (int e = 0; e < E_; ++e) if (e != e0 && acc[e] > m1) { m1 = acc[e]; e1 = e; }
    float s0 = 1.f / (1.f + __expf(m1 - m0));
    scores[tk * 2 + 0] = s0;
    scores[tk * 2 + 1] = 1.f - s0;
    int p0 = atomicAdd(&cnt[e0], 1); list[e0 * NTOK + p0] = tk * 2;
    int p1 = atomicAdd(&cnt[e1], 1); list[e1 * NTOK + p1] = tk * 2 + 1;
  }
}

// ---------------- linear fp32->bf16 convert, 8192 floats per block ----------
__device__ __forceinline__ void cvt_span(const float* __restrict__ src,
                                         u16* __restrict__ dst, int blk) {
  size_t base = (size_t)blk * 8192 + threadIdx.x * 4;
#pragma unroll
  for (int i = 0; i < 8; ++i) {
    float4 v = *(const float4*)(src + base + (size_t)i * 1024);
    ushort4 o;
    o.x = f2bf(v.x); o.y = f2bf(v.y); o.z = f2bf(v.z); o.w = f2bf(v.w);
    *(ushort4*)(dst + base + (size_t)i * 1024) = o;
  }
}

// ---------------- k8-block convert: src fp32 [K][N] -> dst bf16 [kb][N][8] --
// One block = one kb slab (8 rows x N). Reads: 8 full rows, linear.
// Writes: N x 16B units, linear. LDS shuffle in between. Fully streaming.
__device__ __forceinline__ void w8_span(const float* __restrict__ src,
                                        u16* __restrict__ dst, int N, int kb,
                                        void* smem) {
  u16* lds = (u16*)smem;  // [8][N]
  int t = threadIdx.x;
  const float* sp = src + (size_t)kb * 8 * N;
  int total4 = 2 * N;  // (8*N)/4 float4 units
  for (int i = t; i < total4; i += 256) {
    float4 v = *(const float4*)(sp + (size_t)i * 4);
    ushort4 o;
    o.x = f2bf(v.x); o.y = f2bf(v.y); o.z = f2bf(v.z); o.w = f2bf(v.w);
    *(ushort4*)(lds + (size_t)i * 4) = o;
  }
  __syncthreads();
  u16* dp = dst + (size_t)kb * N * 8;
  for (int n = t; n < N; n += 256) {
    uint4 o;
    o.x = (unsigned)lds[0 * N + n] | ((unsigned)lds[1 * N + n] << 16);
    o.y = (unsigned)lds[2 * N + n] | ((unsigned)lds[3 * N + n] << 16);
    o.z = (unsigned)lds[4 * N + n] | ((unsigned)lds[5 * N + n] << 16);
    o.w = (unsigned)lds[6 * N + n] | ((unsigned)lds[7 * N + n] << 16);
    *(uint4*)(dp + (size_t)n * 8) = o;
  }
}

// ================= FAST PATH =================

// prep_a: [0,512) router | [512,768) xb (256 blk = 2M floats, OOB FIXED) |
//         [768,1792) fc1 (8e x 128kb) | [1792,1920) gw | [1920,2048) uw
__global__ __launch_bounds__(256) void prep_a_k(
    const float* __restrict__ x, const float* __restrict__ wr,
    float* __restrict__ scores, int* __restrict__ cnt, int* __restrict__ list,
    u16* __restrict__ xb,
    const float* __restrict__ fc1, const float* __restrict__ gw,
    const float* __restrict__ uw,
    u16* __restrict__ fc1b, u16* __restrict__ gwb, u16* __restrict__ uwb) {
  __shared__ __align__(16) u16 psm[8 * 2048];
  int bid = blockIdx.x;
  if (bid < 512) { router_body(x, wr, scores, cnt, list, bid * 4 + (threadIdx.x >> 6)); return; }
  if (bid < 768) { cvt_span(x, xb, bid - 512); return; }
  if (bid < 1792) {
    int b = bid - 768, e = b >> 7, kb = b & 127;
    w8_span(fc1 + ((size_t)e << 21), fc1b + ((size_t)e << 21), 2048, kb, psm);
  } else if (bid < 1920) {
    w8_span(gw, gwb, 2048, bid - 1792, psm);
  } else {
    w8_span(uw, uwb, 2048, bid - 1920, psm);
  }
}

// prep_b: [0,1024) fc2 (8e x 128kb) | [1024,1280) dw (256 kb)
__global__ __launch_bounds__(256) void prep_b_k(
    const float* __restrict__ fc2, const float* __restrict__ dw,
    u16* __restrict__ fc2b, u16* __restrict__ dwb) {
  __shared__ __align__(16) u16 psm[8 * 2048];
  int bid = blockIdx.x;
  if (bid < 1024) {
    int e = bid >> 7, kb = bid & 127;
    w8_span(fc2 + ((size_t)e << 20), fc2b + ((size_t)e << 20), 1024, kb, psm);
  } else {
    w8_span(dw, dwb, 1024, bid - 1024, psm);
  }
}

// L1: fused SwiGLU GEMMs, dbuf, W8-B staging + plain b128 fragment reads.
// bid<256: G3 dense (gwb/uwb); else G1 expert (fc1b). 128x128, BK=32.
// B LDS tile: [4 kbl][128 n][8 k] u16 (4096 u16 = 8KB). Wave wid stages
// kbl=wid (2 gl16 halves); fragment (fn,lkg) = 16B at kbl=lkg, col*16B.
__global__ __launch_bounds__(256, 2) void swiglu5_k(
    const u16* __restrict__ xb, const int* __restrict__ cnt,
    const int* __restrict__ list, const u16* __restrict__ fc1b,
    const u16* __restrict__ gwb, const u16* __restrict__ uwb,
    u16* __restrict__ act, u16* __restrict__ tmp) {
  __shared__ __align__(16) u16 As[2][4096];
  __shared__ __align__(16) u16 B1s[2][4096];
  __shared__ __align__(16) u16 B2s[2][4096];

  int bid = blockIdx.x;
  int m0, n0, Me, obase = 0, ldo;
  const u16 *B1, *B2;   // W8 layout base incl. n0 (u16*, n-units of 8)
  const int* rowmap = nullptr;
  u16* Out;
  if (bid < 256) {  // G3 shared experts: gw/uw W8 [128kb][2048n][8]
    int mb = bid >> 4, nb = bid & 15;
    m0 = mb * 128; n0 = nb * 128; Me = NTOK;
    B1 = gwb + (size_t)n0 * 8; B2 = uwb + (size_t)n0 * 8;
    Out = tmp; ldo = ISH_;
  } else {  // G1 expert fc1 W8: proj n0, gate 1024+n0
    int b2 = bid - 256; int e = b2 >> 7, r = b2 & 127, mb = r >> 3, nb = r & 7;
    Me = cnt[e]; m0 = mb * 128;
    if (m0 >= Me) return;
    n0 = nb * 128;
    rowmap = list + e * NTOK;
    const u16* fe = fc1b + ((size_t)e << 21);
    B1 = fe + (size_t)n0 * 8;
    B2 = fe + (size_t)(1024 + n0) * 8;
    int off = 0;
    for (int q = 0; q < e; ++q) off += cnt[q];
    obase = off; Out = act; ldo = I_;
  }
  const int ldn = 2048;  // n per kb row in W8
  int t = threadIdx.x, wid = t >> 6, lane = t & 63;
  int wm = wid & 1, wn = wid >> 1, lr = lane & 15, lkg = lane >> 4;
  int cq = lane & 3, crw = lane >> 2;

  const u16* arow[2];
#pragma unroll
  for (int i = 0; i < 2; ++i) {
    int c = wid * 2 + i;
    int rl = m0 + c * 16 + crw;
    int rc = rl < Me ? rl : (Me - 1);
    int tok = rowmap ? (rowmap[rc] >> 1) : rc;
    arow[i] = xb + (size_t)tok * 1024 + cq * 8;
  }
  // per-thread B source bases (kbl = wid folded; lane = n offset)
  const u16* b1base = B1 + ((size_t)wid * ldn + lane) * 8;
  const u16* b2base = B2 + ((size_t)wid * ldn + lane) * 8;

  auto stage = [&](int cb, int kt) {
    size_t ko = (size_t)kt * 4 * ldn * 8;  // u16 offset of K-tile
#pragma unroll
    for (int i = 0; i < 2; ++i)
      gl16(arow[i] + kt * 32, As[cb] + (wid * 2 + i) * 512);
#pragma unroll
    for (int h = 0; h < 2; ++h) {
      gl16(b1base + ko + h * 64 * 8, B1s[cb] + wid * 1024 + h * 512);
      gl16(b2base + ko + h * 64 * 8, B2s[cb] + wid * 1024 + h * 512);
    }
  };

  f32x4 aP[4][4] = {}, aG[4][4] = {};
  auto compute = [&](int cb) {
    bf16x8 af[4];
#pragma unroll
    for (int f = 0; f < 4; ++f)
      af[f] = *(const bf16x8*)(As[cb] + (wm * 64 + f * 16 + lr) * 32 + lkg * 8);
#pragma unroll
    for (int fn = 0; fn < 4; ++fn) {
      int col = wn * 64 + fn * 16 + lr;
      bf16x8 b1 = *(const bf16x8*)(B1s[cb] + lkg * 1024 + col * 8);
      bf16x8 b2 = *(const bf16x8*)(B2s[cb] + lkg * 1024 + col * 8);
#pragma unroll
      for (int fm = 0; fm < 4; ++fm) {
        aP[fm][fn] = mfma16(af[fm], b1, aP[fm][fn]);
        aG[fm][fn] = mfma16(af[fm], b2, aG[fm][fn]);
      }
    }
  };

  stage(0, 0);
  __syncthreads();
  int cur = 0;
  for (int kt = 1; kt < 32; ++kt) {
    stage(cur ^ 1, kt);
    compute(cur);
    __syncthreads();
    cur ^= 1;
  }
  compute(cur);

#pragma unroll
  for (int fm = 0; fm < 4; ++fm)
#pragma unroll
    for (int fn = 0; fn < 4; ++fn)
#pragma unroll
      for (int j = 0; j < 4; ++j) {
        int row = m0 + wm * 64 + fm * 16 + lkg * 4 + j;
        if (row < Me) {
          float p = aP[fm][fn][j], g = aG[fm][fn][j];
          float s = p / (1.f + __expf(-p)) * g;
          Out[(size_t)(obase + row) * ldo + n0 + wn * 64 + fn * 16 + lr] = f2bf(s);
        }
      }
}

// L2: fused fc2 + down GEMMs (BN=128), dbuf, W8-B, fp32 atomicAdd epilogue.
// bid<1024: fc2 expert -> out[token] += v*score. else: down split-K2.
__global__ __launch_bounds__(256, 2) void out5_k(
    const u16* __restrict__ act, const u16* __restrict__ fc2b,
    const u16* __restrict__ tmp, const u16* __restrict__ dwb,
    const int* __restrict__ cnt, const int* __restrict__ list,
    const float* __restrict__ scores, float* __restrict__ out) {
  __shared__ __align__(16) u16 As[2][4096];
  __shared__ __align__(16) u16 Bs[2][4096];

  int bid = blockIdx.x;
  int Me, m0, n0, lda, akoff = 0, mode, e = 0;
  const u16 *Ab, *Bn;
  const int* listE = nullptr;
  if (bid < 1024) {  // fc2 W8 per expert: [128kb][1024n][8]
    e = bid >> 7; int r = bid & 127, mb = r >> 3, nb = r & 7;
    Me = cnt[e]; m0 = mb * 128;
    if (m0 >= Me) return;
    n0 = nb * 128;
    int off = 0;
    for (int q = 0; q < e; ++q) off += cnt[q];
    Ab = act + (size_t)off * 1024; lda = 1024;
    Bn = fc2b + ((size_t)e << 20) + (size_t)n0 * 8;
    listE = list + e * NTOK; mode = 0;
  } else {  // down: dw W8 [256kb][1024n][8]; ks picks kb 128-block
    int r = bid - 1024, ks = r >> 7, rr = r & 127, mb = rr >> 3, nb = rr & 7;
    Me = NTOK; m0 = mb * 128; n0 = nb * 128;
    Ab = tmp; lda = 2048; akoff = ks * 1024;
    Bn = dwb + ((size_t)ks * 128 * 1024 + n0) * 8;
    mode = 1;
  }
  const int ldn = 1024;
  int t = threadIdx.x, wid = t >> 6, lane = t & 63;
  int wm = wid & 1, wn = wid >> 1, lr = lane & 15, lkg = lane >> 4;
  int cq = lane & 3, crw = lane >> 2;

  const u16* arow[2];
#pragma unroll
  for (int i = 0; i < 2; ++i) {
    int c = wid * 2 + i;
    int rl = m0 + c * 16 + crw;
    int rc = rl < Me ? rl : (Me - 1);
    arow[i] = Ab + (size_t)rc * lda + akoff + cq * 8;
  }
  const u16* bbase = Bn + ((size_t)wid * ldn + lane) * 8;

  auto stage = [&](int cb, int kt) {
    size_t ko = (size_t)kt * 4 * ldn * 8;
#pragma unroll
    for (int i = 0; i < 2; ++i)
      gl16(arow[i] + kt * 32, As[cb] + (wid * 2 + i) * 512);
#pragma unroll
    for (int h = 0; h < 2; ++h)
      gl16(bbase + ko + h * 64 * 8, Bs[cb] + wid * 1024 + h * 512);
  };

  f32x4 acc[4][4] = {};
  auto compute = [&](int cb) {
    bf16x8 af[4];
#pragma unroll
    for (int f = 0; f < 4; ++f)
      af[f] = *(const bf16x8*)(As[cb] + (wm * 64 + f * 16 + lr) * 32 + lkg * 8);
#pragma unroll
    for (int fn = 0; fn < 4; ++fn) {
      int col = wn * 64 + fn * 16 + lr;
      bf16x8 bb = *(const bf16x8*)(Bs[cb] + lkg * 1024 + col * 8);
#pragma unroll
      for (int fm = 0; fm < 4; ++fm)
        acc[fm][fn] = mfma16(af[fm], bb, acc[fm][fn]);
    }
  };

  stage(0, 0);
  __syncthreads();
  int cur = 0;
  for (int kt = 1; kt < 32; ++kt) {
    stage(cur ^ 1, kt);
    compute(cur);
    __syncthreads();
    cur ^= 1;
  }
  compute(cur);

#pragma unroll
  for (int fm = 0; fm < 4; ++fm)
#pragma unroll
    for (int fn = 0; fn < 4; ++fn)
#pragma unroll
      for (int j = 0; j < 4; ++j) {
        int row = m0 + wm * 64 + fm * 16 + lkg * 4 + j;
        if (row < Me) {
          float v = acc[fm][fn][j];
          int c = n0 + wn * 64 + fn * 16 + lr;
          if (mode == 0) {
            int slot = listE[row];
            atomicAdd(&out[(size_t)(slot >> 1) * H_ + c], v * scores[slot]);
          } else {
            atomicAdd(&out[(size_t)row * H_ + c], v);
          }
        }
      }
}

// ================= FALLBACK PATH (R1, proven) =================
#define BM 128
#define BN 64
#define BK 32
#define PK (BK + 8)

__global__ void router_k(const float* __restrict__ x, const float* __restrict__ wr,
                         float* __restrict__ scores, int* __restrict__ cnt,
                         int* __restrict__ list) {
  int wid = threadIdx.x >> 6;
  int tk = blockIdx.x * 4 + wid;
  if (tk >= NTOK) return;
  router_body(x, wr, scores, cnt, list, tk);
}

__global__ void offs_k(const int* __restrict__ cnt, int* __restrict__ offs) {
  if (threadIdx.x == 0 && blockIdx.x == 0) {
    int s = 0;
    for (int e = 0; e < E_; ++e) { offs[e] = s; s += cnt[e]; }
  }
}

__global__ void cvt_k(const float* __restrict__ x, u16* __restrict__ xb, int n4) {
  int i = blockIdx.x * blockDim.x + threadIdx.x;
  if (i >= n4) return;
  float4 v = reinterpret_cast<const float4*>(x)[i];
  ushort4 o;
  o.x = f2bf(v.x); o.y = f2bf(v.y); o.z = f2bf(v.z); o.w = f2bf(v.w);
  reinterpret_cast<ushort4*>(xb)[i] = o;
}

template <int EXPERT>
__global__ __launch_bounds__(256) void swiglu_gemm_k(
    const u16* __restrict__ A, int lda,
    const int* __restrict__ list, const int* __restrict__ cnt, const int* __restrict__ offs,
    const float* __restrict__ B1g, const float* __restrict__ B2g, int ldb, long long bstride,
    u16* __restrict__ Out, int ldo, int K) {
  __shared__ u16 As[BM][PK];
  __shared__ u16 Bs[2][BN][PK];
  int e = EXPERT ? blockIdx.z : 0;
  int Me = EXPERT ? cnt[e] : NTOK;
  int m0 = blockIdx.y * BM;
  if (m0 >= Me) return;
  int n0 = blockIdx.x * BN;
  const int* rowmap = EXPERT ? (list + e * NTOK) : nullptr;
  const float* B1 = B1g + (EXPERT ? (long long)e * bstride : 0);
  const float* B2 = B2g + (EXPERT ? (long long)e * bstride : 0);
  int t = threadIdx.x, wid = t >> 6, lane = t & 63;
  int wm = wid & 1, wn = wid >> 1, lr = lane & 15, lkg = lane >> 4;
  f32x4 accP[4][2] = {}, accG[4][2] = {};
  for (int k0 = 0; k0 < K; k0 += BK) {
#pragma unroll
    for (int it = 0; it < 2; ++it) {
      int idx = it * 256 + t, r = idx >> 2, q = idx & 3, row = m0 + r;
      uint4 v = make_uint4(0u, 0u, 0u, 0u);
      if (row < Me) {
        int rg = EXPERT ? (rowmap[row] >> 1) : row;
        v = *reinterpret_cast<const uint4*>(A + (size_t)rg * lda + k0 + q * 8);
      }
      *reinterpret_cast<uint4*>(&As[r][q * 8]) = v;
    }
#pragma unroll
    for (int b = 0; b < 2; ++b) {
      const float* Bp = b ? B2 : B1;
#pragma unroll
      for (int it = 0; it < 2; ++it) {
        int idx = (it * 256 + t) * 4, kr = idx >> 6, c = idx & 63;
        float4 f = *reinterpret_cast<const float4*>(Bp + (size_t)(k0 + kr) * ldb + n0 + c);
        Bs[b][c + 0][kr] = f2bf(f.x); Bs[b][c + 1][kr] = f2bf(f.y);
        Bs[b][c + 2][kr] = f2bf(f.z); Bs[b][c + 3][kr] = f2bf(f.w);
      }
    }
    __syncthreads();
    bf16x8 af[4];
#pragma unroll
    for (int fm = 0; fm < 4; ++fm)
      af[fm] = *reinterpret_cast<const bf16x8*>(&As[wm * 64 + fm * 16 + lr][lkg * 8]);
#pragma unroll
    for (int fn = 0; fn < 2; ++fn) {
      bf16x8 bp = *reinterpret_cast<const bf16x8*>(&Bs[0][wn * 32 + fn * 16 + lr][lkg * 8]);
      bf16x8 bg = *reinterpret_cast<const bf16x8*>(&Bs[1][wn * 32 + fn * 16 + lr][lkg * 8]);
#pragma unroll
      for (int fm = 0; fm < 4; ++fm) {
        accP[fm][fn] = __builtin_amdgcn_mfma_f32_16x16x32_bf16(af[fm], bp, accP[fm][fn], 0, 0, 0);
        accG[fm][fn] = __builtin_amdgcn_mfma_f32_16x16x32_bf16(af[fm], bg, accG[fm][fn], 0, 0, 0);
      }
    }
    __syncthreads();
  }
#pragma unroll
  for (int fm = 0; fm < 4; ++fm)
#pragma unroll
    for (int fn = 0; fn < 2; ++fn)
#pragma unroll
      for (int j = 0; j < 4; ++j) {
        int grow = wm * 64 + fm * 16 + lkg * 4 + j, gcol = wn * 32 + fn * 16 + lr;
        int row = m0 + grow;
        if (row < Me) {
          float p = accP[fm][fn][j], g = accG[fm][fn][j];
          float s = p / (1.f + __expf(-p)) * g;
          int orow = EXPERT ? (offs[e] + row) : row;
          Out[(size_t)orow * ldo + n0 + gcol] = f2bf(s);
        }
      }
}

template <int EXPERT>
__global__ __launch_bounds__(256) void out_gemm_k(
    const u16* __restrict__ A, int lda,
    const int* __restrict__ cnt, const int* __restrict__ offs,
    const int* __restrict__ list, const float* __restrict__ scores,
    const float* __restrict__ Bg, int ldb, long long bstride,
    float* __restrict__ Out, const float* __restrict__ outbuf, int K) {
  __shared__ u16 As[BM][PK];
  __shared__ u16 Bs[BN][PK];
  int e = EXPERT ? blockIdx.z : 0;
  int Me = EXPERT ? cnt[e] : NTOK;
  int m0 = blockIdx.y * BM;
  if (m0 >= Me) return;
  int n0 = blockIdx.x * BN;
  const float* B = Bg + (EXPERT ? (long long)e * bstride : 0);
  int aoff = EXPERT ? offs[e] : 0;
  int t = threadIdx.x, wid = t >> 6, lane = t & 63;
  int wm = wid & 1, wn = wid >> 1, lr = lane & 15, lkg = lane >> 4;
  f32x4 acc[4][2] = {};
  for (int k0 = 0; k0 < K; k0 += BK) {
#pragma unroll
    for (int it = 0; it < 2; ++it) {
      int idx = it * 256 + t, r = idx >> 2, q = idx & 3, row = m0 + r;
      uint4 v = make_uint4(0u, 0u, 0u, 0u);
      if (row < Me)
        v = *reinterpret_cast<const uint4*>(A + (size_t)(aoff + row) * lda + k0 + q * 8);
      *reinterpret_cast<uint4*>(&As[r][q * 8]) = v;
    }
#pragma unroll
    for (int it = 0; it < 2; ++it) {
      int idx = (it * 256 + t) * 4, kr = idx >> 6, c = idx & 63;
      float4 f = *reinterpret_cast<const float4*>(B + (size_t)(k0 + kr) * ldb + n0 + c);
      Bs[c + 0][kr] = f2bf(f.x); Bs[c + 1][kr] = f2bf(f.y);
      Bs[c + 2][kr] = f2bf(f.z); Bs[c + 3][kr] = f2bf(f.w);
    }
    __syncthreads();
    bf16x8 af[4];
#pragma unroll
    for (int fm = 0; fm < 4; ++fm)
      af[fm] = *reinterpret_cast<const bf16x8*>(&As[wm * 64 + fm * 16 + lr][lkg * 8]);
#pragma unroll
    for (int fn = 0; fn < 2; ++fn) {
      bf16x8 bb = *reinterpret_cast<const bf16x8*>(&Bs[wn * 32 + fn * 16 + lr][lkg * 8]);
#pragma unroll
      for (int fm = 0; fm < 4; ++fm)
        acc[fm][fn] = __builtin_amdgcn_mfma_f32_16x16x32_bf16(af[fm], bb, acc[fm][fn], 0, 0, 0);
    }
    __syncthreads();
  }
#pragma unroll
  for (int fm = 0; fm < 4; ++fm)
#pragma unroll
    for (int fn = 0; fn < 2; ++fn)
#pragma unroll
      for (int j = 0; j < 4; ++j) {
        int grow = wm * 64 + fm * 16 + lkg * 4 + j, gcol = wn * 32 + fn * 16 + lr;
        int row = m0 + grow;
        if (row < Me) {
          float v = acc[fm][fn][j];
          int c = n0 + gcol;
          if (EXPERT) {
            int slot = list[e * NTOK + row];
            Out[(size_t)slot * H_ + c] = v * scores[slot];
          } else {
            Out[(size_t)row * H_ + c] =
                v + outbuf[(size_t)(2 * row) * H_ + c] + outbuf[(size_t)(2 * row + 1) * H_ + c];
          }
        }
      }
}

// ---------------------------------------------------------------------------
extern "C" void kernel_launch(void* const* d_in, const int* in_sizes, int n_in,
                              void* d_out, int out_size, void* d_ws, size_t ws_size,
                              hipStream_t stream) {
  const float* x   = (const float*)d_in[0];
  const float* wr  = (const float*)d_in[1];
  const float* fc1 = (const float*)d_in[2];
  const float* fc2 = (const float*)d_in[3];
  const float* gw  = (const float*)d_in[4];
  const float* uw  = (const float*)d_in[5];
  const float* dw  = (const float*)d_in[6];
  float* out = (float*)d_out;
  char* ws = (char*)d_ws;

  const size_t NEED_FAST = 131072ull + (68ull << 20);
  if (ws_size >= NEED_FAST) {
    float* scores = (float*)ws;
    int* cnt  = (int*)(ws + 16384);
    int* list = (int*)(ws + 16512);
    u16* xb   = (u16*)(ws + 131072);
    u16* act  = (u16*)(ws + 131072 + (4ll << 20));
    u16* tmp  = (u16*)(ws + 131072 + (12ll << 20));
    u16* fc1b = (u16*)(ws + 131072 + (20ll << 20));  // 20..52MB (dead after L1)
    u16* gwb  = (u16*)(ws + 131072 + (52ll << 20));  // 52..60MB
    u16* uwb  = (u16*)(ws + 131072 + (60ll << 20));  // 60..68MB
    u16* fc2b = fc1b;                                 // 20..36MB
    u16* dwb  = (u16*)(ws + 131072 + (36ll << 20));  // 36..44MB

    hipMemsetAsync(cnt, 0, 128, stream);
    hipMemsetAsync(out, 0, (size_t)NTOK * H_ * sizeof(float), stream);
    prep_a_k<<<2048, 256, 0, stream>>>(x, wr, scores, cnt, list, xb,
                                       fc1, gw, uw, fc1b, gwb, uwb);
    swiglu5_k<<<1280, 256, 0, stream>>>(xb, cnt, list, fc1b, gwb, uwb, act, tmp);
    prep_b_k<<<1280, 256, 0, stream>>>(fc2, dw, fc2b, dwb);
    out5_k<<<1280, 256, 0, stream>>>(act, fc2b, tmp, dwb, cnt, list, scores, out);
  } else {
    float* scores = (float*)(ws);
    int*   cnt    = (int*)(ws + (16 << 10));
    int*   offs   = (int*)(ws + (16 << 10) + 128);
    int*   list   = (int*)(ws + (16 << 10) + 256);
    u16*   xb     = (u16*)(ws + (96 << 10));
    u16*   act    = (u16*)(ws + (96 << 10) + (4ll << 20));
    u16*   tmp    = (u16*)(ws + (96 << 10) + (12ll << 20));
    float* outbuf = (float*)(ws + (96 << 10) + (20ll << 20));

    hipMemsetAsync(cnt, 0, E_ * sizeof(int), stream);
    router_k<<<NTOK / 4, 256, 0, stream>>>(x, wr, scores, cnt, list);
    offs_k<<<1, 64, 0, stream>>>(cnt, offs);
    cvt_k<<<(NTOK * H_ / 4 + 255) / 256, 256, 0, stream>>>(x, xb, NTOK * H_ / 4);
    swiglu_gemm_k<1><<<dim3(I_ / BN, NTOK / BM, E_), 256, 0, stream>>>(
        xb, H_, list, cnt, offs, fc1, fc1 + I_, 2 * I_, (long long)H_ * 2 * I_, act, I_, H_);
    out_gemm_k<1><<<dim3(H_ / BN, NTOK / BM, E_), 256, 0, stream>>>(
        act, I_, cnt, offs, list, scores, fc2, H_, (long long)I_ * H_, outbuf, nullptr, I_);
    swiglu_gemm_k<0><<<dim3(ISH_ / BN, NTOK / BM, 1), 256, 0, stream>>>(
        xb, H_, nullptr, nullptr, nullptr, gw, uw, ISH_, 0, tmp, ISH_, H_);
    out_gemm_k<0><<<dim3(H_ / BN, NTOK / BM, 1), 256, 0, stream>>>(
        tmp, ISH_, nullptr, nullptr, nullptr, nullptr, dw, H_, 0, out, outbuf, ISH_);
  }
  (void)in_sizes; (void)n_in; (void)out_size;
}